// Round 6
// baseline (1568.588 us; speedup 1.0000x reference)
//
#include <hip/hip_runtime.h>

#define NN 100000
#define EE 1600000
#define HH 128
#define MM 256
#define LL 6
#define GG 512
#define SCAN_NB ((NN + 1023) / 1024)

typedef __attribute__((ext_vector_type(8))) short short8;
typedef __attribute__((ext_vector_type(4))) float floatx4;

__device__ __forceinline__ float swishf(float v) {
    return v / (1.0f + __expf(-v));
}

__device__ __forceinline__ unsigned short f2bf(float f) {
    unsigned u = __builtin_bit_cast(unsigned, f);
    unsigned r = u + 0x7FFFu + ((u >> 16) & 1u);
    return (unsigned short)(r >> 16);
}

__device__ __forceinline__ float bf2f(unsigned short u) {
    return __builtin_bit_cast(float, (unsigned)u << 16);
}

__device__ __forceinline__ float2 bf2f2(unsigned u) {
    float2 r;
    r.x = __builtin_bit_cast(float, u << 16);
    r.y = __builtin_bit_cast(float, u & 0xFFFF0000u);
    return r;
}

// blocked activation layout: [C/16][N][16] bf16
__device__ __forceinline__ size_t blka(int c, int r) {
    return ((size_t)(c >> 4) * NN + r) * 16 + (c & 15);
}

__device__ __forceinline__ void unpack8(uint4 v, float* a) {
    float2 p0 = bf2f2(v.x), p1 = bf2f2(v.y), p2 = bf2f2(v.z), p3 = bf2f2(v.w);
    a[0] = p0.x; a[1] = p0.y; a[2] = p1.x; a[3] = p1.y;
    a[4] = p2.x; a[5] = p2.y; a[6] = p3.x; a[7] = p3.y;
}

__device__ __forceinline__ uint4 pack8(const float* o) {
    uint4 pk;
    pk.x = (unsigned)f2bf(o[0]) | ((unsigned)f2bf(o[1]) << 16);
    pk.y = (unsigned)f2bf(o[2]) | ((unsigned)f2bf(o[3]) << 16);
    pk.z = (unsigned)f2bf(o[4]) | ((unsigned)f2bf(o[5]) << 16);
    pk.w = (unsigned)f2bf(o[6]) | ((unsigned)f2bf(o[7]) << 16);
    return pk;
}

// h blocked: thread = (slice p, node n), computes 16 channels, writes 32 B.
__global__ void k_embed(const float* __restrict__ x, const float* __restrict__ z_embed,
                        const float* __restrict__ ew, const float* __restrict__ eb,
                        unsigned short* __restrict__ hb) {
    int idx = blockIdx.x * blockDim.x + threadIdx.x;
    if (idx >= NN * 8) return;
    int p = idx / NN;
    int n = idx - p * NN;
    const float* xr = x + (size_t)n * 4;
    int z = (int)xr[0];
    float x1 = xr[1], x2 = xr[2], x3 = xr[3];
    const float* ze = z_embed + (size_t)z * HH + p * 16;
    float o[16];
#pragma unroll
    for (int k = 0; k < 16; ++k) {
        int c = p * 16 + k;
        o[k] = ze[k] + x1 * ew[c * 3 + 0] + x2 * ew[c * 3 + 1] + x3 * ew[c * 3 + 2] + eb[c];
    }
    unsigned short* dst = hb + ((size_t)p * NN + n) * 16;
    *(uint4*)dst = pack8(o);
    *(uint4*)(dst + 8) = pack8(o + 8);
}

// cast 3 weight tensors fp32->bf16 in one launch
__global__ void k_f2bf3(const float* __restrict__ s1, unsigned short* __restrict__ d1, int n1,
                        const float* __restrict__ s2, unsigned short* __restrict__ d2, int n2,
                        const float* __restrict__ s3, unsigned short* __restrict__ d3, int n3) {
    int i = blockIdx.x * blockDim.x + threadIdx.x;
    if (i < n1) {
        d1[i] = f2bf(s1[i]);
    } else if (i < n1 + n2) {
        d2[i - n1] = f2bf(s2[i - n1]);
    } else if (i < n1 + n2 + n3) {
        d3[i - n1 - n2] = f2bf(s3[i - n1 - n2]);
    }
}

// XCD-partitioned degree count
__global__ __launch_bounds__(256) void k_degree_p(const int* __restrict__ dst,
                                                  int* __restrict__ deg) {
    int part = blockIdx.x & 7;
    int blk = blockIdx.x >> 3;
    int nb = gridDim.x >> 3;
    int lo = (int)((long long)part * NN / 8);
    int hi = (int)((long long)(part + 1) * NN / 8);
    for (int e = blk * 256 + threadIdx.x; e < EE; e += nb * 256) {
        int d = dst[e];
        if (d >= lo && d < hi) atomicAdd(&deg[d], 1);
    }
}

__global__ void k_dinv(const int* __restrict__ deg, float* __restrict__ dinv) {
    int n = blockIdx.x * blockDim.x + threadIdx.x;
    if (n < NN) dinv[n] = rsqrtf((float)(deg[n] + 1));
}

__global__ void k_scan1(const int* __restrict__ deg, int* __restrict__ bsum) {
    __shared__ int sd[256];
    int t = threadIdx.x;
    int base = blockIdx.x * 1024 + t * 4;
    int s = 0;
#pragma unroll
    for (int j = 0; j < 4; ++j) {
        int i = base + j;
        if (i < NN) s += deg[i];
    }
    sd[t] = s;
    __syncthreads();
    for (int off = 128; off > 0; off >>= 1) {
        if (t < off) sd[t] += sd[t + off];
        __syncthreads();
    }
    if (t == 0) bsum[blockIdx.x] = sd[0];
}

__global__ void k_scan2(const int* __restrict__ bsum, int* __restrict__ boff) {
    __shared__ int sd[128];
    int t = threadIdx.x;
    int v = (t < SCAN_NB) ? bsum[t] : 0;
    sd[t] = v;
    __syncthreads();
    for (int off = 1; off < 128; off <<= 1) {
        int u = (t >= off) ? sd[t - off] : 0;
        __syncthreads();
        sd[t] += u;
        __syncthreads();
    }
    boff[t] = sd[t] - v;  // exclusive
}

__global__ void k_scan3(const int* __restrict__ deg, const int* __restrict__ boff,
                        int* __restrict__ rowptr) {
    __shared__ int sd[256];
    int t = threadIdx.x;
    int base = blockIdx.x * 1024 + t * 4;
    int v[4];
    int s = 0;
#pragma unroll
    for (int j = 0; j < 4; ++j) {
        int i = base + j;
        v[j] = (i < NN) ? deg[i] : 0;
        s += v[j];
    }
    sd[t] = s;
    __syncthreads();
    for (int off = 1; off < 256; off <<= 1) {
        int u = (t >= off) ? sd[t - off] : 0;
        __syncthreads();
        sd[t] += u;
        __syncthreads();
    }
    int run = boff[blockIdx.x] + sd[t] - s;
#pragma unroll
    for (int j = 0; j < 4; ++j) {
        int i = base + j;
        if (i < NN) rowptr[i] = run;
        if (i == NN - 1) rowptr[NN] = run + v[j];
        run += v[j];
    }
}

// XCD-partitioned CSR fill
__global__ __launch_bounds__(256) void k_fill_p(const int* __restrict__ ei,
                                                const int* __restrict__ rowptr,
                                                int* __restrict__ cursor,
                                                int* __restrict__ col) {
    int part = blockIdx.x & 7;
    int blk = blockIdx.x >> 3;
    int nb = gridDim.x >> 3;
    int lo = (int)((long long)part * NN / 8);
    int hi = (int)((long long)(part + 1) * NN / 8);
    for (int e = blk * 256 + threadIdx.x; e < EE; e += nb * 256) {
        int d = ei[EE + e];
        if (d >= lo && d < hi) {
            int p = atomicAdd(&cursor[d], 1);
            col[rowptr[d] + p] = ei[e];
        }
    }
}

__global__ void k_gptr(const int* __restrict__ batch, int* __restrict__ gptr) {
    int n = blockIdx.x * blockDim.x + threadIdx.x;
    if (n >= NN) return;
    int b = batch[n];
    int pb = (n == 0) ? -1 : batch[n - 1];
    for (int g = pb + 1; g <= b; ++g) gptr[g] = n;
    if (n == NN - 1) {
        for (int g = b + 1; g <= GG; ++g) gptr[g] = NN;
    }
}

// MFMA GEMM. A blocked bf16 [K/16][N][16]; B row-major bf16 [Cout][K] staged to LDS
// with permuted rows so each lane's 4 MFMA fragments yield 4 ADJACENT output cols
// -> packed 8 B epilogue stores. One barrier total.
// EPI 0: Cb = bf16(acc * dinv[r])     blocked      (aux = dinv fp32)
// EPI 1: Cb = bf16(swish(acc+bias))   blocked
// EPI 2: o = swish(acc+bias)+res_blk; Cb = bf16(o) blocked; if(writeF) Cf fp32 row-major
template <int K, int EPI>
__global__ __launch_bounds__(256) void k_gemm(const unsigned short* __restrict__ A,
                                              const unsigned short* __restrict__ B,
                                              const float* __restrict__ bias, const void* aux,
                                              float* Cf, unsigned short* __restrict__ Cb,
                                              int writeF) {
    __shared__ unsigned short Bs[128][K + 8];
    const int tid = threadIdx.x;
    const int wave = tid >> 6;
    const int lane = tid & 63;
    const int quad = lane >> 4;
    const int l16 = lane & 15;
    const int wr = (wave & 1) << 6;
    const int wc = (wave >> 1) << 6;
    const int rowBase = blockIdx.x * 128;
    const int colBase = blockIdx.y * 128;

    // stage B: physical col (colBase + r), r = base64 + q*4 + j -> LDS row base64 + j*16 + q
    for (int i = tid; i < 128 * (K / 8); i += 256) {
        int r = i / (K / 8);
        int kk = (i % (K / 8)) * 8;
        int rho = (r & 64) | ((r & 3) << 4) | ((r >> 2) & 15);
        *(uint4*)(&Bs[rho][kk]) = *(const uint4*)(B + (size_t)(colBase + r) * K + kk);
    }

    floatx4 acc[4][4];
    const floatx4 zed = {0.f, 0.f, 0.f, 0.f};
#pragma unroll
    for (int i = 0; i < 4; ++i)
#pragma unroll
        for (int j = 0; j < 4; ++j) acc[i][j] = zed;

    int ar[4];
#pragma unroll
    for (int i = 0; i < 4; ++i) {
        int r = rowBase + wr + (i << 4) + l16;
        ar[i] = r < NN ? r : NN - 1;
    }

    __syncthreads();  // B ready; no further barriers

#pragma unroll
    for (int ks = 0; ks < K / 32; ++ks) {
        int k = (ks << 5) + (quad << 3);
        short8 a[4], b[4];
#pragma unroll
        for (int i = 0; i < 4; ++i)
            a[i] = *(const short8*)(A + ((size_t)(k >> 4) * NN + ar[i]) * 16 + (k & 15));
#pragma unroll
        for (int j = 0; j < 4; ++j) b[j] = *(const short8*)(&Bs[wc + (j << 4) + l16][k]);
#pragma unroll
        for (int i = 0; i < 4; ++i)
#pragma unroll
            for (int j = 0; j < 4; ++j)
                acc[i][j] =
                    __builtin_amdgcn_mfma_f32_16x16x32_bf16(a[i], b[j], acc[i][j], 0, 0, 0);
    }

    const int c0 = colBase + wc + (l16 << 2);  // 4 adjacent output cols
    float bv[4];
    if (EPI >= 1) {
        float4 b4 = *(const float4*)(bias + c0);
        bv[0] = b4.x; bv[1] = b4.y; bv[2] = b4.z; bv[3] = b4.w;
    }
#pragma unroll
    for (int i = 0; i < 4; ++i) {
        int rb = rowBase + wr + (i << 4) + (quad << 2);
        float4 dv4;
        if (EPI == 0 && rb + 3 < NN) dv4 = *(const float4*)((const float*)aux + rb);
#pragma unroll
        for (int reg = 0; reg < 4; ++reg) {
            int r = rb + reg;
            if (r < NN) {
                float o[4];
#pragma unroll
                for (int j = 0; j < 4; ++j) o[j] = acc[i][j][reg];
                if (EPI == 0) {
                    float dv = (rb + 3 < NN) ? ((const float*)&dv4)[reg]
                                             : ((const float*)aux)[r];
#pragma unroll
                    for (int j = 0; j < 4; ++j) o[j] *= dv;
                } else if (EPI == 1) {
#pragma unroll
                    for (int j = 0; j < 4; ++j) o[j] = swishf(o[j] + bv[j]);
                } else {
                    uint2 rv = *(const uint2*)((const unsigned short*)aux + blka(c0, r));
                    float2 r01 = bf2f2(rv.x), r23 = bf2f2(rv.y);
                    o[0] = swishf(o[0] + bv[0]) + r01.x;
                    o[1] = swishf(o[1] + bv[1]) + r01.y;
                    o[2] = swishf(o[2] + bv[2]) + r23.x;
                    o[3] = swishf(o[3] + bv[3]) + r23.y;
                    if (writeF) {
                        *(float4*)(Cf + (size_t)r * HH + c0) =
                            make_float4(o[0], o[1], o[2], o[3]);
                    }
                }
                uint2 pk;
                pk.x = (unsigned)f2bf(o[0]) | ((unsigned)f2bf(o[1]) << 16);
                pk.y = (unsigned)f2bf(o[2]) | ((unsigned)f2bf(o[3]) << 16);
                *(uint2*)(Cb + blka(c0, r)) = pk;
            }
        }
    }
}

// XCD-sliced gather, full-width loads: part p gathers only y slice p ([NN][16] bf16,
// 3.2 MB, L2-resident). 2 lanes per node x 16 B -> 1 KB per gather instruction
// (32 nodes/wave), no cross-lane reduction. 2-deep load pipeline.
__global__ __launch_bounds__(256) void k_agg(const unsigned short* __restrict__ y,
                                             const int* __restrict__ rowptr,
                                             const int* __restrict__ col,
                                             const float* __restrict__ dinv,
                                             const float* __restrict__ cb,
                                             unsigned short* __restrict__ agg) {
    int p = blockIdx.x & 7;
    int chunk = blockIdx.x >> 3;
    int wave = threadIdx.x >> 6;
    int lane = threadIdx.x & 63;
    int pair = lane >> 1;
    int half = lane & 1;
    int d = (chunk * 4 + wave) * 32 + pair;
    if (d >= NN) return;
    const unsigned short* ys = y + (size_t)p * NN * 16;
    uint4 v = *(const uint4*)(ys + (size_t)d * 16 + (half << 3));
    float ax[8];
    unpack8(v, ax);
    int beg = rowptr[d];
    int end = rowptr[d + 1];
    int e = beg;
    for (; e + 1 < end; e += 2) {
        int s0 = col[e];
        int s1 = col[e + 1];
        uint4 w0 = *(const uint4*)(ys + (size_t)s0 * 16 + (half << 3));
        uint4 w1 = *(const uint4*)(ys + (size_t)s1 * 16 + (half << 3));
        float b0[8], b1[8];
        unpack8(w0, b0);
        unpack8(w1, b1);
#pragma unroll
        for (int k = 0; k < 8; ++k) ax[k] += b0[k] + b1[k];
    }
    if (e < end) {
        uint4 w0 = *(const uint4*)(ys + (size_t)col[e] * 16 + (half << 3));
        float b0[8];
        unpack8(w0, b0);
#pragma unroll
        for (int k = 0; k < 8; ++k) ax[k] += b0[k];
    }
    float dv = dinv[d];
    int c0 = (p << 4) + (half << 3);
    float4 c4a = *(const float4*)(cb + c0);
    float4 c4b = *(const float4*)(cb + c0 + 4);
    float o[8];
    o[0] = ax[0] * dv + c4a.x; o[1] = ax[1] * dv + c4a.y;
    o[2] = ax[2] * dv + c4a.z; o[3] = ax[3] * dv + c4a.w;
    o[4] = ax[4] * dv + c4b.x; o[5] = ax[5] * dv + c4b.y;
    o[6] = ax[6] * dv + c4b.z; o[7] = ax[7] * dv + c4b.w;
    *(uint4*)(agg + (size_t)p * NN * 16 + (size_t)d * 16 + (half << 3)) = pack8(o);
}

// per-(graph, part) stats from blocked agg (XCD-local slice)
__global__ __launch_bounds__(256) void k_stats(const unsigned short* __restrict__ agg,
                                               const int* __restrict__ gptr,
                                               const float* __restrict__ ms,
                                               float* __restrict__ gmean,
                                               float* __restrict__ grstd) {
    __shared__ float s1[256];
    __shared__ float s2[256];
    int p = blockIdx.x & 7;
    int g = blockIdx.x >> 3;
    int t = threadIdx.x;
    int cc = t & 15;
    int pr = t >> 4;
    int beg = gptr[g];
    int end = gptr[g + 1];
    const unsigned short* ap = agg + (size_t)p * NN * 16;
    float S1 = 0.f, S2 = 0.f;
    for (int n = beg + pr; n < end; n += 16) {
        float v = bf2f(ap[(size_t)n * 16 + cc]);
        S1 += v;
        S2 += v * v;
    }
    s1[t] = S1;
    s2[t] = S2;
    __syncthreads();
    if (t < 16) {
        float T1 = 0.f, T2 = 0.f;
#pragma unroll
        for (int k = 0; k < 16; ++k) {
            T1 += s1[k * 16 + t];
            T2 += s2[k * 16 + t];
        }
        int cnt = end - beg;
        float inv = 1.0f / (float)(cnt > 0 ? cnt : 1);
        float m = T1 * inv;
        int c = p * 16 + t;
        float msc = ms[c];
        float var = T2 * inv - msc * (2.0f - msc) * m * m;
        gmean[g * HH + c] = m;
        grstd[g * HH + c] = rsqrtf(var + 1e-5f);
    }
}

// norm+swish on XCD-local blocked slice; blocked in, blocked out
__global__ __launch_bounds__(256) void k_normswish(const unsigned short* __restrict__ agg,
                                                   const int* __restrict__ batch,
                                                   const float* __restrict__ gamma,
                                                   const float* __restrict__ beta,
                                                   const float* __restrict__ ms,
                                                   const float* __restrict__ gmean,
                                                   const float* __restrict__ grstd,
                                                   unsigned short* __restrict__ ha) {
    int p = blockIdx.x & 7;
    int chunk = blockIdx.x >> 3;
    int t = threadIdx.x;
    int n = chunk * 128 + (t >> 1);
    if (n >= NN) return;
    int half = t & 1;
    int c0 = (p << 4) + (half << 3);
    int g = batch[n];
    size_t base = ((size_t)p * NN + n) * 16 + (half << 3);
    uint4 a = *(const uint4*)(agg + base);
    float av[8];
    unpack8(a, av);
    const float* gm = gmean + g * HH + c0;
    const float* gr = grstd + g * HH + c0;
    float o[8];
#pragma unroll
    for (int j = 0; j < 8; ++j) {
        int c = c0 + j;
        float sub = av[j] - ms[c] * gm[j];
        float hn = gamma[c] * sub * gr[j] + beta[c];
        o[j] = swishf(hn);
    }
    *(uint4*)(ha + base) = pack8(o);
}

extern "C" void kernel_launch(void* const* d_in, const int* in_sizes, int n_in,
                              void* d_out, int out_size, void* d_ws, size_t ws_size,
                              hipStream_t stream) {
    const float* x = (const float*)d_in[0];
    const int* ei = (const int*)d_in[1];
    const int* batch = (const int*)d_in[2];
    const float* z_embed = (const float*)d_in[3];
    const float* extra_w = (const float*)d_in[4];
    const float* extra_b = (const float*)d_in[5];
    const float* conv_w = (const float*)d_in[6];
    const float* conv_b = (const float*)d_in[7];
    const float* gamma = (const float*)d_in[8];
    const float* beta = (const float*)d_in[9];
    const float* mean_scale = (const float*)d_in[10];
    const float* mlp_w1 = (const float*)d_in[11];
    const float* mlp_b1 = (const float*)d_in[12];
    const float* mlp_w2 = (const float*)d_in[13];
    const float* mlp_b2 = (const float*)d_in[14];
    float* h_out = (float*)d_out;

    char* wsB = (char*)d_ws;
    size_t off = 0;
    auto alloc = [&](size_t bytes) -> void* {
        void* p = (void*)(wsB + off);
        off = (off + bytes + 255) & ~(size_t)255;
        return p;
    };
    float* dinv = (float*)alloc((size_t)NN * 4);
    int* deg = (int*)alloc((size_t)NN * 4);
    int* cursor = (int*)alloc((size_t)NN * 4);
    int* rowptr = (int*)alloc((size_t)(NN + 1) * 4);
    int* bsum = (int*)alloc(128 * 4);
    int* boff = (int*)alloc(128 * 4);
    int* col = (int*)alloc((size_t)EE * 4);
    int* gptr = (int*)alloc((size_t)(GG + 1) * 4);
    float* gmean = (float*)alloc((size_t)GG * HH * 4);
    float* grstd = (float*)alloc((size_t)GG * HH * 4);
    unsigned short* wb =
        (unsigned short*)alloc((size_t)(LL * (HH * HH + MM * HH + HH * MM)) * 2);
    unsigned short* cwb = wb;
    unsigned short* w1b = wb + (size_t)LL * HH * HH;
    unsigned short* w2b = w1b + (size_t)LL * MM * HH;
    unsigned short* hb = (unsigned short*)alloc((size_t)NN * HH * 2);    // blocked residual
    unsigned short* ybuf = (unsigned short*)alloc((size_t)NN * HH * 2);  // blocked y then ha
    unsigned short* tb = (unsigned short*)alloc((size_t)NN * MM * 2);    // blocked t / agg
    unsigned short* aggb = tb;  // blocked agg [8][NN][16] (consumed before t written)

    hipMemsetAsync(deg, 0, (size_t)NN * 4, stream);
    hipMemsetAsync(cursor, 0, (size_t)NN * 4, stream);

    k_embed<<<(NN * 8 + 255) / 256, 256, 0, stream>>>(x, z_embed, extra_w, extra_b, hb);
    {
        int n1 = LL * HH * HH, n2 = LL * MM * HH, n3 = LL * HH * MM;
        int nt = n1 + n2 + n3;
        k_f2bf3<<<(nt + 255) / 256, 256, 0, stream>>>(conv_w, cwb, n1, mlp_w1, w1b, n2,
                                                      mlp_w2, w2b, n3);
    }
    k_degree_p<<<1024, 256, 0, stream>>>(ei + EE, deg);
    k_dinv<<<(NN + 255) / 256, 256, 0, stream>>>(deg, dinv);
    k_scan1<<<SCAN_NB, 256, 0, stream>>>(deg, bsum);
    k_scan2<<<1, 128, 0, stream>>>(bsum, boff);
    k_scan3<<<SCAN_NB, 256, 0, stream>>>(deg, boff, rowptr);
    k_fill_p<<<1024, 256, 0, stream>>>(ei, rowptr, cursor, col);
    k_gptr<<<(NN + 255) / 256, 256, 0, stream>>>(batch, gptr);

    dim3 g1((NN + 127) / 128, 1);
    dim3 g2((NN + 127) / 128, 2);
    int part8 = ((NN + 127) / 128) * 8;
    for (int i = 0; i < LL; ++i) {
        k_gemm<HH, 0><<<g1, 256, 0, stream>>>(hb, cwb + (size_t)i * HH * HH, nullptr, dinv,
                                              nullptr, ybuf, 0);
        k_agg<<<part8, 256, 0, stream>>>(ybuf, rowptr, col, dinv, conv_b + (size_t)i * HH,
                                         aggb);
        k_stats<<<GG * 8, 256, 0, stream>>>(aggb, gptr, mean_scale + (size_t)i * HH, gmean,
                                            grstd);
        k_normswish<<<part8, 256, 0, stream>>>(aggb, batch, gamma + (size_t)i * HH,
                                               beta + (size_t)i * HH,
                                               mean_scale + (size_t)i * HH, gmean, grstd,
                                               ybuf);
        k_gemm<HH, 1><<<g2, 256, 0, stream>>>(ybuf, w1b + (size_t)i * MM * HH,
                                              mlp_b1 + (size_t)i * MM, nullptr, nullptr, tb, 0);
        k_gemm<MM, 2><<<g1, 256, 0, stream>>>(tb, w2b + (size_t)i * HH * MM,
                                              mlp_b2 + (size_t)i * HH, hb, h_out, hb,
                                              i == LL - 1 ? 1 : 0);
    }
}

// Round 7
// 1444.880 us; speedup vs baseline: 1.0856x; 1.0856x over previous
//
#include <hip/hip_runtime.h>

#define NN 100000
#define EE 1600000
#define HH 128
#define MM 256
#define LL 6
#define GG 512
#define SCAN_NB ((NN + 1023) / 1024)

typedef __attribute__((ext_vector_type(8))) short short8;
typedef __attribute__((ext_vector_type(4))) float floatx4;

__device__ __forceinline__ float swishf(float v) {
    return v / (1.0f + __expf(-v));
}

__device__ __forceinline__ unsigned short f2bf(float f) {
    unsigned u = __builtin_bit_cast(unsigned, f);
    unsigned r = u + 0x7FFFu + ((u >> 16) & 1u);
    return (unsigned short)(r >> 16);
}

__device__ __forceinline__ float bf2f(unsigned short u) {
    return __builtin_bit_cast(float, (unsigned)u << 16);
}

__device__ __forceinline__ float2 bf2f2(unsigned u) {
    float2 r;
    r.x = __builtin_bit_cast(float, u << 16);
    r.y = __builtin_bit_cast(float, u & 0xFFFF0000u);
    return r;
}

__device__ __forceinline__ uint4 pack8(const float* o) {
    uint4 pk;
    pk.x = (unsigned)f2bf(o[0]) | ((unsigned)f2bf(o[1]) << 16);
    pk.y = (unsigned)f2bf(o[2]) | ((unsigned)f2bf(o[3]) << 16);
    pk.z = (unsigned)f2bf(o[4]) | ((unsigned)f2bf(o[5]) << 16);
    pk.w = (unsigned)f2bf(o[6]) | ((unsigned)f2bf(o[7]) << 16);
    return pk;
}

// h[n,c] (row-major bf16) = z_embed[z[n],c] + x[:,1:]@ew^T + eb
__global__ void k_embed(const float* __restrict__ x, const float* __restrict__ z_embed,
                        const float* __restrict__ ew, const float* __restrict__ eb,
                        unsigned short* __restrict__ hb) {
    int idx = blockIdx.x * blockDim.x + threadIdx.x;
    if (idx >= NN * 32) return;
    int n = idx >> 5;
    int c0 = (idx & 31) << 2;
    const float* xr = x + (size_t)n * 4;
    int z = (int)xr[0];
    float x1 = xr[1], x2 = xr[2], x3 = xr[3];
    const float* ze = z_embed + (size_t)z * HH + c0;
    float o[4];
#pragma unroll
    for (int j = 0; j < 4; ++j) {
        int c = c0 + j;
        o[j] = ze[j] + x1 * ew[c * 3 + 0] + x2 * ew[c * 3 + 1] + x3 * ew[c * 3 + 2] + eb[c];
    }
    uint2 p;
    p.x = (unsigned)f2bf(o[0]) | ((unsigned)f2bf(o[1]) << 16);
    p.y = (unsigned)f2bf(o[2]) | ((unsigned)f2bf(o[3]) << 16);
    *(uint2*)(hb + (size_t)n * HH + c0) = p;
}

__global__ void k_f2bf3(const float* __restrict__ s1, unsigned short* __restrict__ d1, int n1,
                        const float* __restrict__ s2, unsigned short* __restrict__ d2, int n2,
                        const float* __restrict__ s3, unsigned short* __restrict__ d3, int n3) {
    int i = blockIdx.x * blockDim.x + threadIdx.x;
    if (i < n1) {
        d1[i] = f2bf(s1[i]);
    } else if (i < n1 + n2) {
        d2[i - n1] = f2bf(s2[i - n1]);
    } else if (i < n1 + n2 + n3) {
        d3[i - n1 - n2] = f2bf(s3[i - n1 - n2]);
    }
}

__global__ __launch_bounds__(256) void k_degree_p(const int* __restrict__ dst,
                                                  int* __restrict__ deg) {
    int part = blockIdx.x & 7;
    int blk = blockIdx.x >> 3;
    int nb = gridDim.x >> 3;
    int lo = (int)((long long)part * NN / 8);
    int hi = (int)((long long)(part + 1) * NN / 8);
    for (int e = blk * 256 + threadIdx.x; e < EE; e += nb * 256) {
        int d = dst[e];
        if (d >= lo && d < hi) atomicAdd(&deg[d], 1);
    }
}

__global__ void k_dinv(const int* __restrict__ deg, float* __restrict__ dinv) {
    int n = blockIdx.x * blockDim.x + threadIdx.x;
    if (n < NN) dinv[n] = rsqrtf((float)(deg[n] + 1));
}

__global__ void k_scan1(const int* __restrict__ deg, int* __restrict__ bsum) {
    __shared__ int sd[256];
    int t = threadIdx.x;
    int base = blockIdx.x * 1024 + t * 4;
    int s = 0;
#pragma unroll
    for (int j = 0; j < 4; ++j) {
        int i = base + j;
        if (i < NN) s += deg[i];
    }
    sd[t] = s;
    __syncthreads();
    for (int off = 128; off > 0; off >>= 1) {
        if (t < off) sd[t] += sd[t + off];
        __syncthreads();
    }
    if (t == 0) bsum[blockIdx.x] = sd[0];
}

__global__ void k_scan2(const int* __restrict__ bsum, int* __restrict__ boff) {
    __shared__ int sd[128];
    int t = threadIdx.x;
    int v = (t < SCAN_NB) ? bsum[t] : 0;
    sd[t] = v;
    __syncthreads();
    for (int off = 1; off < 128; off <<= 1) {
        int u = (t >= off) ? sd[t - off] : 0;
        __syncthreads();
        sd[t] += u;
        __syncthreads();
    }
    boff[t] = sd[t] - v;  // exclusive
}

__global__ void k_scan3(const int* __restrict__ deg, const int* __restrict__ boff,
                        int* __restrict__ rowptr) {
    __shared__ int sd[256];
    int t = threadIdx.x;
    int base = blockIdx.x * 1024 + t * 4;
    int v[4];
    int s = 0;
#pragma unroll
    for (int j = 0; j < 4; ++j) {
        int i = base + j;
        v[j] = (i < NN) ? deg[i] : 0;
        s += v[j];
    }
    sd[t] = s;
    __syncthreads();
    for (int off = 1; off < 256; off <<= 1) {
        int u = (t >= off) ? sd[t - off] : 0;
        __syncthreads();
        sd[t] += u;
        __syncthreads();
    }
    int run = boff[blockIdx.x] + sd[t] - s;
#pragma unroll
    for (int j = 0; j < 4; ++j) {
        int i = base + j;
        if (i < NN) rowptr[i] = run;
        if (i == NN - 1) rowptr[NN] = run + v[j];
        run += v[j];
    }
}

__global__ __launch_bounds__(256) void k_fill_p(const int* __restrict__ ei,
                                                const int* __restrict__ rowptr,
                                                int* __restrict__ cursor,
                                                int* __restrict__ col) {
    int part = blockIdx.x & 7;
    int blk = blockIdx.x >> 3;
    int nb = gridDim.x >> 3;
    int lo = (int)((long long)part * NN / 8);
    int hi = (int)((long long)(part + 1) * NN / 8);
    for (int e = blk * 256 + threadIdx.x; e < EE; e += nb * 256) {
        int d = ei[EE + e];
        if (d >= lo && d < hi) {
            int p = atomicAdd(&cursor[d], 1);
            col[rowptr[d] + p] = ei[e];
        }
    }
}

__global__ void k_gptr(const int* __restrict__ batch, int* __restrict__ gptr) {
    int n = blockIdx.x * blockDim.x + threadIdx.x;
    if (n >= NN) return;
    int b = batch[n];
    int pb = (n == 0) ? -1 : batch[n - 1];
    for (int g = pb + 1; g <= b; ++g) gptr[g] = n;
    if (n == NN - 1) {
        for (int g = b + 1; g <= GG; ++g) gptr[g] = NN;
    }
}

// Conv GEMM: y[N,128] = bf16( (h @ Wc^T) * dinv[row] ). Row-major A; B staged to LDS
// permuted (lane owns 4 adjacent out cols -> 8 B stores); one barrier, barrier-free K-loop.
__global__ __launch_bounds__(256) void k_conv(const unsigned short* __restrict__ A,
                                              const unsigned short* __restrict__ B,
                                              const float* __restrict__ dinv,
                                              unsigned short* __restrict__ Cb) {
    __shared__ unsigned short Bs[128][HH + 8];
    const int tid = threadIdx.x;
    const int wave = tid >> 6;
    const int lane = tid & 63;
    const int quad = lane >> 4;
    const int l16 = lane & 15;
    const int wr = (wave & 1) << 6;
    const int wc = (wave >> 1) << 6;
    const int rowBase = blockIdx.x * 128;

    // stage B permuted: physical col r = base64 + q*4 + j -> LDS row base64 + j*16 + q
    for (int i = tid; i < 128 * (HH / 8); i += 256) {
        int r = i / (HH / 8);
        int kk = (i % (HH / 8)) * 8;
        int rho = (r & 64) | ((r & 3) << 4) | ((r >> 2) & 15);
        *(uint4*)(&Bs[rho][kk]) = *(const uint4*)(B + (size_t)r * HH + kk);
    }

    floatx4 acc[4][4];
    const floatx4 zed = {0.f, 0.f, 0.f, 0.f};
#pragma unroll
    for (int i = 0; i < 4; ++i)
#pragma unroll
        for (int j = 0; j < 4; ++j) acc[i][j] = zed;

    int ar[4];
#pragma unroll
    for (int i = 0; i < 4; ++i) {
        int r = rowBase + wr + (i << 4) + l16;
        ar[i] = r < NN ? r : NN - 1;
    }

    __syncthreads();

#pragma unroll
    for (int ks = 0; ks < HH / 32; ++ks) {
        int k = (ks << 5) + (quad << 3);
        short8 a[4], b[4];
#pragma unroll
        for (int i = 0; i < 4; ++i) a[i] = *(const short8*)(A + (size_t)ar[i] * HH + k);
#pragma unroll
        for (int j = 0; j < 4; ++j) b[j] = *(const short8*)(&Bs[wc + (j << 4) + l16][k]);
#pragma unroll
        for (int i = 0; i < 4; ++i)
#pragma unroll
            for (int j = 0; j < 4; ++j)
                acc[i][j] =
                    __builtin_amdgcn_mfma_f32_16x16x32_bf16(a[i], b[j], acc[i][j], 0, 0, 0);
    }

    const int c0 = wc + (l16 << 2);  // 4 adjacent output cols
#pragma unroll
    for (int i = 0; i < 4; ++i) {
        int rb = rowBase + wr + (i << 4) + (quad << 2);
#pragma unroll
        for (int reg = 0; reg < 4; ++reg) {
            int r = rb + reg;
            if (r < NN) {
                float dv = dinv[r];
                float o[4];
#pragma unroll
                for (int j = 0; j < 4; ++j) o[j] = acc[i][j][reg] * dv;
                uint2 pk;
                pk.x = (unsigned)f2bf(o[0]) | ((unsigned)f2bf(o[1]) << 16);
                pk.y = (unsigned)f2bf(o[2]) | ((unsigned)f2bf(o[3]) << 16);
                *(uint2*)(Cb + (size_t)r * HH + c0) = pk;
            }
        }
    }
}

// Fused MLP: h' = swish(swish(ha@W1^T + b1)@W2^T + b2) + h_res. Block = 64 rows.
// t (64x256 bf16) lives in LDS; W1/W2 fragments direct from L2 with permuted col
// mapping (lane owns adjacent out cols). One internal barrier.
__global__ __launch_bounds__(256) void k_mlp(const unsigned short* __restrict__ ha,
                                             const unsigned short* __restrict__ W1,
                                             const float* __restrict__ b1,
                                             const unsigned short* __restrict__ W2,
                                             const float* __restrict__ b2,
                                             unsigned short* __restrict__ hb,
                                             float* __restrict__ h_out, int writeF) {
    __shared__ unsigned short ts[64][MM + 8];
    const int tid = threadIdx.x;
    const int wave = tid >> 6;
    const int lane = tid & 63;
    const int quad = lane >> 4;
    const int l16 = lane & 15;
    const int wrh = (wave & 1) << 5;   // 32-row half
    const int rowBase = blockIdx.x * 64;

    // ---------- phase A: t = swish(ha @ W1^T + b1), wave tile 32 x 128 ----------
    const int wch = (wave >> 1) << 7;  // 128-col half of 256
    floatx4 acc1[2][8];
    const floatx4 zed = {0.f, 0.f, 0.f, 0.f};
#pragma unroll
    for (int i = 0; i < 2; ++i)
#pragma unroll
        for (int j = 0; j < 8; ++j) acc1[i][j] = zed;

    int ar[2];
#pragma unroll
    for (int i = 0; i < 2; ++i) {
        int r = rowBase + wrh + (i << 4) + l16;
        ar[i] = r < NN ? r : NN - 1;
    }

#pragma unroll
    for (int ks = 0; ks < HH / 32; ++ks) {
        int k = (ks << 5) + (quad << 3);
        short8 a[2], b[8];
#pragma unroll
        for (int i = 0; i < 2; ++i) a[i] = *(const short8*)(ha + (size_t)ar[i] * HH + k);
#pragma unroll
        for (int j = 0; j < 8; ++j) {
            int pc = wch + (l16 << 3) + j;  // permuted: lane owns 8 adjacent t-cols
            b[j] = *(const short8*)(W1 + (size_t)pc * HH + k);
        }
#pragma unroll
        for (int i = 0; i < 2; ++i)
#pragma unroll
            for (int j = 0; j < 8; ++j)
                acc1[i][j] =
                    __builtin_amdgcn_mfma_f32_16x16x32_bf16(a[i], b[j], acc1[i][j], 0, 0, 0);
    }

    const int c0a = wch + (l16 << 3);
    float b1v[8];
    {
        float4 u = *(const float4*)(b1 + c0a);
        float4 v = *(const float4*)(b1 + c0a + 4);
        b1v[0] = u.x; b1v[1] = u.y; b1v[2] = u.z; b1v[3] = u.w;
        b1v[4] = v.x; b1v[5] = v.y; b1v[6] = v.z; b1v[7] = v.w;
    }
#pragma unroll
    for (int i = 0; i < 2; ++i) {
#pragma unroll
        for (int reg = 0; reg < 4; ++reg) {
            int lr = wrh + (i << 4) + (quad << 2) + reg;
            float o[8];
#pragma unroll
            for (int j = 0; j < 8; ++j) o[j] = swishf(acc1[i][j][reg] + b1v[j]);
            *(uint4*)(&ts[lr][c0a]) = pack8(o);
        }
    }
    __syncthreads();

    // ---------- phase B: h' = swish(t @ W2^T + b2) + res, wave tile 32 x 64 ----------
    const int wc2 = (wave >> 1) << 6;  // 64-col half of 128
    floatx4 acc2[2][4];
#pragma unroll
    for (int i = 0; i < 2; ++i)
#pragma unroll
        for (int j = 0; j < 4; ++j) acc2[i][j] = zed;

#pragma unroll
    for (int ks = 0; ks < MM / 32; ++ks) {
        int k = (ks << 5) + (quad << 3);
        short8 a[2], b[4];
#pragma unroll
        for (int i = 0; i < 2; ++i)
            a[i] = *(const short8*)(&ts[wrh + (i << 4) + l16][k]);
#pragma unroll
        for (int j = 0; j < 4; ++j) {
            int pc = wc2 + (l16 << 2) + j;
            b[j] = *(const short8*)(W2 + (size_t)pc * MM + k);
        }
#pragma unroll
        for (int i = 0; i < 2; ++i)
#pragma unroll
            for (int j = 0; j < 4; ++j)
                acc2[i][j] =
                    __builtin_amdgcn_mfma_f32_16x16x32_bf16(a[i], b[j], acc2[i][j], 0, 0, 0);
    }

    const int c0 = wc2 + (l16 << 2);
    float4 b2v = *(const float4*)(b2 + c0);
    float bv[4] = {b2v.x, b2v.y, b2v.z, b2v.w};
#pragma unroll
    for (int i = 0; i < 2; ++i) {
        int rb = rowBase + wrh + (i << 4) + (quad << 2);
#pragma unroll
        for (int reg = 0; reg < 4; ++reg) {
            int r = rb + reg;
            if (r < NN) {
                uint2 rv = *(const uint2*)(hb + (size_t)r * HH + c0);
                float2 r01 = bf2f2(rv.x), r23 = bf2f2(rv.y);
                float o[4];
                o[0] = swishf(acc2[i][0][reg] + bv[0]) + r01.x;
                o[1] = swishf(acc2[i][1][reg] + bv[1]) + r01.y;
                o[2] = swishf(acc2[i][2][reg] + bv[2]) + r23.x;
                o[3] = swishf(acc2[i][3][reg] + bv[3]) + r23.y;
                uint2 pk;
                pk.x = (unsigned)f2bf(o[0]) | ((unsigned)f2bf(o[1]) << 16);
                pk.y = (unsigned)f2bf(o[2]) | ((unsigned)f2bf(o[3]) << 16);
                *(uint2*)(hb + (size_t)r * HH + c0) = pk;
                if (writeF)
                    *(float4*)(h_out + (size_t)r * HH + c0) =
                        make_float4(o[0], o[1], o[2], o[3]);
            }
        }
    }
}

// Wide-load gather (row-major): wave = 1 node; 16 lanes x 16 B cover the 256 B row;
// 4 edge-groups in flight; butterfly shfl reduce; packed 16 B store.
__global__ __launch_bounds__(256) void k_agg(const unsigned short* __restrict__ y,
                                             const int* __restrict__ rowptr,
                                             const int* __restrict__ col,
                                             const float* __restrict__ dinv,
                                             const float* __restrict__ cb,
                                             unsigned short* __restrict__ agg) {
    int w = threadIdx.x >> 6;
    int lane = threadIdx.x & 63;
    int d = blockIdx.x * 4 + w;
    if (d >= NN) return;
    int grp = lane >> 4;
    int l16 = lane & 15;
    const uint4* yv = (const uint4*)y;  // row = 16 uint4
    float acc[8];
#pragma unroll
    for (int j = 0; j < 8; ++j) acc[j] = 0.f;
    if (grp == 0) {
        uint4 v = yv[(size_t)d * 16 + l16];
        float2 p0 = bf2f2(v.x), p1 = bf2f2(v.y), p2 = bf2f2(v.z), p3 = bf2f2(v.w);
        acc[0] = p0.x; acc[1] = p0.y; acc[2] = p1.x; acc[3] = p1.y;
        acc[4] = p2.x; acc[5] = p2.y; acc[6] = p3.x; acc[7] = p3.y;
    }
    int beg = rowptr[d];
    int end = rowptr[d + 1];
    for (int e = beg + grp; e < end; e += 4) {
        int s = col[e];
        uint4 v = yv[(size_t)s * 16 + l16];
        float2 p0 = bf2f2(v.x), p1 = bf2f2(v.y), p2 = bf2f2(v.z), p3 = bf2f2(v.w);
        acc[0] += p0.x; acc[1] += p0.y; acc[2] += p1.x; acc[3] += p1.y;
        acc[4] += p2.x; acc[5] += p2.y; acc[6] += p3.x; acc[7] += p3.y;
    }
#pragma unroll
    for (int j = 0; j < 8; ++j) {
        acc[j] += __shfl_xor(acc[j], 16, 64);
        acc[j] += __shfl_xor(acc[j], 32, 64);
    }
    if (grp == 0) {
        float dv = dinv[d];
        float4 c0 = *(const float4*)(cb + l16 * 8);
        float4 c1 = *(const float4*)(cb + l16 * 8 + 4);
        float o[8];
        o[0] = acc[0] * dv + c0.x; o[1] = acc[1] * dv + c0.y;
        o[2] = acc[2] * dv + c0.z; o[3] = acc[3] * dv + c0.w;
        o[4] = acc[4] * dv + c1.x; o[5] = acc[5] * dv + c1.y;
        o[6] = acc[6] * dv + c1.z; o[7] = acc[7] * dv + c1.w;
        *(uint4*)(agg + (size_t)d * HH + l16 * 8) = pack8(o);
    }
}

// per-graph mean/rstd from bf16 agg; var = E[a^2] - ms*(2-ms)*mean^2
__global__ __launch_bounds__(512) void k_stats(const unsigned short* __restrict__ agg,
                                               const int* __restrict__ gptr,
                                               const float* __restrict__ ms,
                                               float* __restrict__ gmean,
                                               float* __restrict__ grstd) {
    __shared__ float s1[512];
    __shared__ float s2[512];
    int g = blockIdx.x;
    int t = threadIdx.x;
    int c = t & 127;
    int part = t >> 7;
    int beg = gptr[g];
    int end = gptr[g + 1];
    float S1 = 0.f, S2 = 0.f;
    for (int n = beg + part; n < end; n += 4) {
        float v = bf2f(agg[(size_t)n * HH + c]);
        S1 += v;
        S2 += v * v;
    }
    s1[t] = S1;
    s2[t] = S2;
    __syncthreads();
    if (part == 0) {
        S1 = (s1[c] + s1[c + 128]) + (s1[c + 256] + s1[c + 384]);
        S2 = (s2[c] + s2[c + 128]) + (s2[c + 256] + s2[c + 384]);
        int cnt = end - beg;
        float inv = 1.0f / (float)(cnt > 0 ? cnt : 1);
        float m = S1 * inv;
        float msc = ms[c];
        float var = S2 * inv - msc * (2.0f - msc) * m * m;
        gmean[g * HH + c] = m;
        grstd[g * HH + c] = rsqrtf(var + 1e-5f);
    }
}

__global__ void k_normswish(const unsigned short* __restrict__ agg,
                            const int* __restrict__ batch, const float* __restrict__ gamma,
                            const float* __restrict__ beta, const float* __restrict__ ms,
                            const float* __restrict__ gmean, const float* __restrict__ grstd,
                            unsigned short* __restrict__ ha) {
    int idx = blockIdx.x * blockDim.x + threadIdx.x;
    if (idx >= NN * 32) return;
    int n = idx >> 5;
    int c0 = (idx & 31) << 2;
    int g = batch[n];
    uint2 ain = *(const uint2*)(agg + (size_t)n * HH + c0);
    float2 a01 = bf2f2(ain.x);
    float2 a23 = bf2f2(ain.y);
    float av[4] = {a01.x, a01.y, a23.x, a23.y};
    unsigned short o[4];
#pragma unroll
    for (int j = 0; j < 4; ++j) {
        int c = c0 + j;
        float sub = av[j] - ms[c] * gmean[g * HH + c];
        float hn = gamma[c] * sub * grstd[g * HH + c] + beta[c];
        o[j] = f2bf(swishf(hn));
    }
    uint2 p;
    p.x = (unsigned)o[0] | ((unsigned)o[1] << 16);
    p.y = (unsigned)o[2] | ((unsigned)o[3] << 16);
    *(uint2*)(ha + (size_t)n * HH + c0) = p;
}

extern "C" void kernel_launch(void* const* d_in, const int* in_sizes, int n_in,
                              void* d_out, int out_size, void* d_ws, size_t ws_size,
                              hipStream_t stream) {
    const float* x = (const float*)d_in[0];
    const int* ei = (const int*)d_in[1];
    const int* batch = (const int*)d_in[2];
    const float* z_embed = (const float*)d_in[3];
    const float* extra_w = (const float*)d_in[4];
    const float* extra_b = (const float*)d_in[5];
    const float* conv_w = (const float*)d_in[6];
    const float* conv_b = (const float*)d_in[7];
    const float* gamma = (const float*)d_in[8];
    const float* beta = (const float*)d_in[9];
    const float* mean_scale = (const float*)d_in[10];
    const float* mlp_w1 = (const float*)d_in[11];
    const float* mlp_b1 = (const float*)d_in[12];
    const float* mlp_w2 = (const float*)d_in[13];
    const float* mlp_b2 = (const float*)d_in[14];
    float* h_out = (float*)d_out;

    char* wsB = (char*)d_ws;
    size_t off = 0;
    auto alloc = [&](size_t bytes) -> void* {
        void* p = (void*)(wsB + off);
        off = (off + bytes + 255) & ~(size_t)255;
        return p;
    };
    float* dinv = (float*)alloc((size_t)NN * 4);
    int* deg = (int*)alloc((size_t)NN * 4);
    int* cursor = (int*)alloc((size_t)NN * 4);
    int* rowptr = (int*)alloc((size_t)(NN + 1) * 4);
    int* bsum = (int*)alloc(128 * 4);
    int* boff = (int*)alloc(128 * 4);
    int* col = (int*)alloc((size_t)EE * 4);
    int* gptr = (int*)alloc((size_t)(GG + 1) * 4);
    float* gmean = (float*)alloc((size_t)GG * HH * 4);
    float* grstd = (float*)alloc((size_t)GG * HH * 4);
    unsigned short* wb =
        (unsigned short*)alloc((size_t)(LL * (HH * HH + MM * HH + HH * MM)) * 2);
    unsigned short* cwb = wb;
    unsigned short* w1b = wb + (size_t)LL * HH * HH;
    unsigned short* w2b = w1b + (size_t)LL * MM * HH;
    unsigned short* hb = (unsigned short*)alloc((size_t)NN * HH * 2);    // bf16 residual/state
    unsigned short* ybuf = (unsigned short*)alloc((size_t)NN * HH * 2);  // y_bf then ha_bf
    unsigned short* aggb = (unsigned short*)alloc((size_t)NN * HH * 2);  // agg bf16

    hipMemsetAsync(deg, 0, (size_t)NN * 4, stream);
    hipMemsetAsync(cursor, 0, (size_t)NN * 4, stream);

    k_embed<<<(NN * 32 + 255) / 256, 256, 0, stream>>>(x, z_embed, extra_w, extra_b, hb);
    {
        int n1 = LL * HH * HH, n2 = LL * MM * HH, n3 = LL * HH * MM;
        int nt = n1 + n2 + n3;
        k_f2bf3<<<(nt + 255) / 256, 256, 0, stream>>>(conv_w, cwb, n1, mlp_w1, w1b, n2,
                                                      mlp_w2, w2b, n3);
    }
    k_degree_p<<<1024, 256, 0, stream>>>(ei + EE, deg);
    k_dinv<<<(NN + 255) / 256, 256, 0, stream>>>(deg, dinv);
    k_scan1<<<SCAN_NB, 256, 0, stream>>>(deg, bsum);
    k_scan2<<<1, 128, 0, stream>>>(bsum, boff);
    k_scan3<<<SCAN_NB, 256, 0, stream>>>(deg, boff, rowptr);
    k_fill_p<<<1024, 256, 0, stream>>>(ei, rowptr, cursor, col);
    k_gptr<<<(NN + 255) / 256, 256, 0, stream>>>(batch, gptr);

    int gconv = (NN + 127) / 128;
    int gmlp = (NN + 63) / 64;
    for (int i = 0; i < LL; ++i) {
        k_conv<<<gconv, 256, 0, stream>>>(hb, cwb + (size_t)i * HH * HH, dinv, ybuf);
        k_agg<<<(NN + 3) / 4, 256, 0, stream>>>(ybuf, rowptr, col, dinv,
                                                conv_b + (size_t)i * HH, aggb);
        k_stats<<<GG, 512, 0, stream>>>(aggb, gptr, mean_scale + (size_t)i * HH, gmean, grstd);
        k_normswish<<<(NN * 32 + 255) / 256, 256, 0, stream>>>(
            aggb, batch, gamma + (size_t)i * HH, beta + (size_t)i * HH,
            mean_scale + (size_t)i * HH, gmean, grstd, ybuf);
        k_mlp<<<gmlp, 256, 0, stream>>>(ybuf, w1b + (size_t)i * MM * HH,
                                        mlp_b1 + (size_t)i * MM, w2b + (size_t)i * HH * MM,
                                        mlp_b2 + (size_t)i * HH, hb, h_out,
                                        i == LL - 1 ? 1 : 0);
    }
}

// Round 8
// 1415.784 us; speedup vs baseline: 1.1079x; 1.0206x over previous
//
#include <hip/hip_runtime.h>

#define NN 100000
#define EE 1600000
#define HH 128
#define MM 256
#define LL 6
#define GG 512
#define SCAN_NB ((NN + 1023) / 1024)

typedef __attribute__((ext_vector_type(8))) short short8;
typedef __attribute__((ext_vector_type(4))) float floatx4;

__device__ __forceinline__ float swishf(float v) {
    return v / (1.0f + __expf(-v));
}

__device__ __forceinline__ unsigned short f2bf(float f) {
    unsigned u = __builtin_bit_cast(unsigned, f);
    unsigned r = u + 0x7FFFu + ((u >> 16) & 1u);
    return (unsigned short)(r >> 16);
}

__device__ __forceinline__ float bf2f(unsigned short u) {
    return __builtin_bit_cast(float, (unsigned)u << 16);
}

__device__ __forceinline__ float2 bf2f2(unsigned u) {
    float2 r;
    r.x = __builtin_bit_cast(float, u << 16);
    r.y = __builtin_bit_cast(float, u & 0xFFFF0000u);
    return r;
}

__device__ __forceinline__ void unpack8(uint4 v, float* a) {
    float2 p0 = bf2f2(v.x), p1 = bf2f2(v.y), p2 = bf2f2(v.z), p3 = bf2f2(v.w);
    a[0] = p0.x; a[1] = p0.y; a[2] = p1.x; a[3] = p1.y;
    a[4] = p2.x; a[5] = p2.y; a[6] = p3.x; a[7] = p3.y;
}

__device__ __forceinline__ uint4 pack8(const float* o) {
    uint4 pk;
    pk.x = (unsigned)f2bf(o[0]) | ((unsigned)f2bf(o[1]) << 16);
    pk.y = (unsigned)f2bf(o[2]) | ((unsigned)f2bf(o[3]) << 16);
    pk.z = (unsigned)f2bf(o[4]) | ((unsigned)f2bf(o[5]) << 16);
    pk.w = (unsigned)f2bf(o[6]) | ((unsigned)f2bf(o[7]) << 16);
    return pk;
}

__device__ __forceinline__ uint2 pack4(const float* o) {
    uint2 pk;
    pk.x = (unsigned)f2bf(o[0]) | ((unsigned)f2bf(o[1]) << 16);
    pk.y = (unsigned)f2bf(o[2]) | ((unsigned)f2bf(o[3]) << 16);
    return pk;
}

// h[n,c] (row-major bf16) = z_embed[z[n],c] + x[:,1:]@ew^T + eb
__global__ void k_embed(const float* __restrict__ x, const float* __restrict__ z_embed,
                        const float* __restrict__ ew, const float* __restrict__ eb,
                        unsigned short* __restrict__ hb) {
    int idx = blockIdx.x * blockDim.x + threadIdx.x;
    if (idx >= NN * 32) return;
    int n = idx >> 5;
    int c0 = (idx & 31) << 2;
    const float* xr = x + (size_t)n * 4;
    int z = (int)xr[0];
    float x1 = xr[1], x2 = xr[2], x3 = xr[3];
    const float* ze = z_embed + (size_t)z * HH + c0;
    float o[4];
#pragma unroll
    for (int j = 0; j < 4; ++j) {
        int c = c0 + j;
        o[j] = ze[j] + x1 * ew[c * 3 + 0] + x2 * ew[c * 3 + 1] + x3 * ew[c * 3 + 2] + eb[c];
    }
    *(uint2*)(hb + (size_t)n * HH + c0) = pack4(o);
}

__global__ void k_f2bf3(const float* __restrict__ s1, unsigned short* __restrict__ d1, int n1,
                        const float* __restrict__ s2, unsigned short* __restrict__ d2, int n2,
                        const float* __restrict__ s3, unsigned short* __restrict__ d3, int n3) {
    int i = blockIdx.x * blockDim.x + threadIdx.x;
    if (i < n1) {
        d1[i] = f2bf(s1[i]);
    } else if (i < n1 + n2) {
        d2[i - n1] = f2bf(s2[i - n1]);
    } else if (i < n1 + n2 + n3) {
        d3[i - n1 - n2] = f2bf(s3[i - n1 - n2]);
    }
}

__global__ __launch_bounds__(256) void k_degree_p(const int* __restrict__ dst,
                                                  int* __restrict__ deg) {
    int part = blockIdx.x & 7;
    int blk = blockIdx.x >> 3;
    int nb = gridDim.x >> 3;
    int lo = (int)((long long)part * NN / 8);
    int hi = (int)((long long)(part + 1) * NN / 8);
    for (int e = blk * 256 + threadIdx.x; e < EE; e += nb * 256) {
        int d = dst[e];
        if (d >= lo && d < hi) atomicAdd(&deg[d], 1);
    }
}

__global__ void k_dinv(const int* __restrict__ deg, float* __restrict__ dinv) {
    int n = blockIdx.x * blockDim.x + threadIdx.x;
    if (n < NN) dinv[n] = rsqrtf((float)(deg[n] + 1));
}

__global__ void k_scan1(const int* __restrict__ deg, int* __restrict__ bsum) {
    __shared__ int sd[256];
    int t = threadIdx.x;
    int base = blockIdx.x * 1024 + t * 4;
    int s = 0;
#pragma unroll
    for (int j = 0; j < 4; ++j) {
        int i = base + j;
        if (i < NN) s += deg[i];
    }
    sd[t] = s;
    __syncthreads();
    for (int off = 128; off > 0; off >>= 1) {
        if (t < off) sd[t] += sd[t + off];
        __syncthreads();
    }
    if (t == 0) bsum[blockIdx.x] = sd[0];
}

__global__ void k_scan2(const int* __restrict__ bsum, int* __restrict__ boff) {
    __shared__ int sd[128];
    int t = threadIdx.x;
    int v = (t < SCAN_NB) ? bsum[t] : 0;
    sd[t] = v;
    __syncthreads();
    for (int off = 1; off < 128; off <<= 1) {
        int u = (t >= off) ? sd[t - off] : 0;
        __syncthreads();
        sd[t] += u;
        __syncthreads();
    }
    boff[t] = sd[t] - v;  // exclusive
}

__global__ void k_scan3(const int* __restrict__ deg, const int* __restrict__ boff,
                        int* __restrict__ rowptr) {
    __shared__ int sd[256];
    int t = threadIdx.x;
    int base = blockIdx.x * 1024 + t * 4;
    int v[4];
    int s = 0;
#pragma unroll
    for (int j = 0; j < 4; ++j) {
        int i = base + j;
        v[j] = (i < NN) ? deg[i] : 0;
        s += v[j];
    }
    sd[t] = s;
    __syncthreads();
    for (int off = 1; off < 256; off <<= 1) {
        int u = (t >= off) ? sd[t - off] : 0;
        __syncthreads();
        sd[t] += u;
        __syncthreads();
    }
    int run = boff[blockIdx.x] + sd[t] - s;
#pragma unroll
    for (int j = 0; j < 4; ++j) {
        int i = base + j;
        if (i < NN) rowptr[i] = run;
        if (i == NN - 1) rowptr[NN] = run + v[j];
        run += v[j];
    }
}

__global__ __launch_bounds__(256) void k_fill_p(const int* __restrict__ ei,
                                                const int* __restrict__ rowptr,
                                                int* __restrict__ cursor,
                                                int* __restrict__ col) {
    int part = blockIdx.x & 7;
    int blk = blockIdx.x >> 3;
    int nb = gridDim.x >> 3;
    int lo = (int)((long long)part * NN / 8);
    int hi = (int)((long long)(part + 1) * NN / 8);
    for (int e = blk * 256 + threadIdx.x; e < EE; e += nb * 256) {
        int d = ei[EE + e];
        if (d >= lo && d < hi) {
            int p = atomicAdd(&cursor[d], 1);
            col[rowptr[d] + p] = ei[e];
        }
    }
}

__global__ void k_gptr(const int* __restrict__ batch, int* __restrict__ gptr) {
    int n = blockIdx.x * blockDim.x + threadIdx.x;
    if (n >= NN) return;
    int b = batch[n];
    int pb = (n == 0) ? -1 : batch[n - 1];
    for (int g = pb + 1; g <= b; ++g) gptr[g] = n;
    if (n == NN - 1) {
        for (int g = b + 1; g <= GG; ++g) gptr[g] = NN;
    }
}

// Conv GEMM (layer 0 only): y = bf16((h @ Wc^T) * dinv[row]).
__global__ __launch_bounds__(256) void k_conv(const unsigned short* __restrict__ A,
                                              const unsigned short* __restrict__ B,
                                              const float* __restrict__ dinv,
                                              unsigned short* __restrict__ Cb) {
    __shared__ unsigned short Bs[128][HH + 8];
    const int tid = threadIdx.x;
    const int wave = tid >> 6;
    const int lane = tid & 63;
    const int quad = lane >> 4;
    const int l16 = lane & 15;
    const int wr = (wave & 1) << 6;
    const int wc = (wave >> 1) << 6;
    const int rowBase = blockIdx.x * 128;

    for (int i = tid; i < 128 * (HH / 8); i += 256) {
        int r = i / (HH / 8);
        int kk = (i % (HH / 8)) * 8;
        int rho = (r & 64) | ((r & 3) << 4) | ((r >> 2) & 15);
        *(uint4*)(&Bs[rho][kk]) = *(const uint4*)(B + (size_t)r * HH + kk);
    }

    floatx4 acc[4][4];
    const floatx4 zed = {0.f, 0.f, 0.f, 0.f};
#pragma unroll
    for (int i = 0; i < 4; ++i)
#pragma unroll
        for (int j = 0; j < 4; ++j) acc[i][j] = zed;

    int ar[4];
#pragma unroll
    for (int i = 0; i < 4; ++i) {
        int r = rowBase + wr + (i << 4) + l16;
        ar[i] = r < NN ? r : NN - 1;
    }

    __syncthreads();

#pragma unroll
    for (int ks = 0; ks < HH / 32; ++ks) {
        int k = (ks << 5) + (quad << 3);
        short8 a[4], b[4];
#pragma unroll
        for (int i = 0; i < 4; ++i) a[i] = *(const short8*)(A + (size_t)ar[i] * HH + k);
#pragma unroll
        for (int j = 0; j < 4; ++j) b[j] = *(const short8*)(&Bs[wc + (j << 4) + l16][k]);
#pragma unroll
        for (int i = 0; i < 4; ++i)
#pragma unroll
            for (int j = 0; j < 4; ++j)
                acc[i][j] =
                    __builtin_amdgcn_mfma_f32_16x16x32_bf16(a[i], b[j], acc[i][j], 0, 0, 0);
    }

    const int c0 = wc + (l16 << 2);
#pragma unroll
    for (int i = 0; i < 4; ++i) {
        int rb = rowBase + wr + (i << 4) + (quad << 2);
#pragma unroll
        for (int reg = 0; reg < 4; ++reg) {
            int r = rb + reg;
            if (r < NN) {
                float dv = dinv[r];
                float o[4];
#pragma unroll
                for (int j = 0; j < 4; ++j) o[j] = acc[i][j][reg] * dv;
                *(uint2*)(Cb + (size_t)r * HH + c0) = pack4(o);
            }
        }
    }
}

// Wide-load gather (row-major): wave = 1 node; 16 lanes x 16 B cover the 256 B row.
__global__ __launch_bounds__(256) void k_agg(const unsigned short* __restrict__ y,
                                             const int* __restrict__ rowptr,
                                             const int* __restrict__ col,
                                             const float* __restrict__ dinv,
                                             const float* __restrict__ cb,
                                             unsigned short* __restrict__ agg) {
    int w = threadIdx.x >> 6;
    int lane = threadIdx.x & 63;
    int d = blockIdx.x * 4 + w;
    if (d >= NN) return;
    int grp = lane >> 4;
    int l16 = lane & 15;
    const uint4* yv = (const uint4*)y;
    float acc[8];
#pragma unroll
    for (int j = 0; j < 8; ++j) acc[j] = 0.f;
    if (grp == 0) {
        uint4 v = yv[(size_t)d * 16 + l16];
        unpack8(v, acc);
    }
    int beg = rowptr[d];
    int end = rowptr[d + 1];
    for (int e = beg + grp; e < end; e += 4) {
        int s = col[e];
        uint4 v = yv[(size_t)s * 16 + l16];
        float b0[8];
        unpack8(v, b0);
#pragma unroll
        for (int k = 0; k < 8; ++k) acc[k] += b0[k];
    }
#pragma unroll
    for (int j = 0; j < 8; ++j) {
        acc[j] += __shfl_xor(acc[j], 16, 64);
        acc[j] += __shfl_xor(acc[j], 32, 64);
    }
    if (grp == 0) {
        float dv = dinv[d];
        float4 c0 = *(const float4*)(cb + l16 * 8);
        float4 c1 = *(const float4*)(cb + l16 * 8 + 4);
        float o[8];
        o[0] = acc[0] * dv + c0.x; o[1] = acc[1] * dv + c0.y;
        o[2] = acc[2] * dv + c0.z; o[3] = acc[3] * dv + c0.w;
        o[4] = acc[4] * dv + c1.x; o[5] = acc[5] * dv + c1.y;
        o[6] = acc[6] * dv + c1.z; o[7] = acc[7] * dv + c1.w;
        *(uint4*)(agg + (size_t)d * HH + l16 * 8) = pack8(o);
    }
}

// per-graph stats -> affine coeffs: c1 = gamma*rstd, c0 = beta - c1*ms*mean
__global__ __launch_bounds__(512) void k_stats(const unsigned short* __restrict__ agg,
                                               const int* __restrict__ gptr,
                                               const float* __restrict__ ms,
                                               const float* __restrict__ gamma,
                                               const float* __restrict__ beta,
                                               float* __restrict__ c1,
                                               float* __restrict__ c0) {
    __shared__ float s1[512];
    __shared__ float s2[512];
    int g = blockIdx.x;
    int t = threadIdx.x;
    int c = t & 127;
    int part = t >> 7;
    int beg = gptr[g];
    int end = gptr[g + 1];
    float S1 = 0.f, S2 = 0.f;
    for (int n = beg + part; n < end; n += 4) {
        float v = bf2f(agg[(size_t)n * HH + c]);
        S1 += v;
        S2 += v * v;
    }
    s1[t] = S1;
    s2[t] = S2;
    __syncthreads();
    if (part == 0) {
        S1 = (s1[c] + s1[c + 128]) + (s1[c + 256] + s1[c + 384]);
        S2 = (s2[c] + s2[c + 128]) + (s2[c + 256] + s2[c + 384]);
        int cnt = end - beg;
        float inv = 1.0f / (float)(cnt > 0 ? cnt : 1);
        float m = S1 * inv;
        float msc = ms[c];
        float var = S2 * inv - msc * (2.0f - msc) * m * m;
        float rstd = rsqrtf(var + 1e-5f);
        float c1v = gamma[c] * rstd;
        c1[g * HH + c] = c1v;
        c0[g * HH + c] = beta[c] - c1v * msc * m;
    }
}

// Mega layer kernel: ha = swish(c1*agg + c0) built inline as MFMA A-fragments;
// t = swish(ha@W1^T+b1) in LDS; h' = swish(t@W2^T+b2)+res -> hb (+h_out last layer);
// phase C (if doConv): y_next = bf16((h' @ Wc^T)*dinv) with h' staged in LDS.
// Block = 64 rows, 4 waves. Phase A j-split halves AGPR pressure.
__global__ __launch_bounds__(256) void k_mega(const unsigned short* __restrict__ agg,
                                              const int* __restrict__ batch,
                                              const float* __restrict__ c1,
                                              const float* __restrict__ c0,
                                              const unsigned short* __restrict__ W1,
                                              const float* __restrict__ b1,
                                              const unsigned short* __restrict__ W2,
                                              const float* __restrict__ b2,
                                              const unsigned short* __restrict__ Wc,
                                              const float* __restrict__ dinv,
                                              unsigned short* __restrict__ hb,
                                              float* __restrict__ h_out,
                                              unsigned short* __restrict__ y_out, int writeF,
                                              int doConv) {
    __shared__ unsigned short smem[64 * (MM + 8)];  // t: pitch 264; reused as h': pitch 136
    const int tid = threadIdx.x;
    const int wave = tid >> 6;
    const int lane = tid & 63;
    const int quad = lane >> 4;
    const int l16 = lane & 15;
    const int wrh = (wave & 1) << 5;   // row half (0/32)
    const int wch = (wave >> 1) << 7;  // t-col half (0/128)
    const int wc2 = (wave >> 1) << 6;  // out-col half (0/64)
    const int rowBase = blockIdx.x * 64;
    const floatx4 zed = {0.f, 0.f, 0.f, 0.f};

    // ---- phase A: build normswished A-fragments, t = swish(.@W1^T + b1) ----
    int ar[2], gi[2];
#pragma unroll
    for (int i = 0; i < 2; ++i) {
        int r = rowBase + wrh + (i << 4) + l16;
        ar[i] = r < NN ? r : NN - 1;
        gi[i] = batch[ar[i]];
    }

    short8 a_all[4][2];
#pragma unroll
    for (int ks = 0; ks < 4; ++ks) {
        int k = (ks << 5) + (quad << 3);
#pragma unroll
        for (int i = 0; i < 2; ++i) {
            uint4 raw = *(const uint4*)(agg + (size_t)ar[i] * HH + k);
            float v[8];
            unpack8(raw, v);
            const float* c1p = c1 + gi[i] * HH + k;
            const float* c0p = c0 + gi[i] * HH + k;
            float4 c1a = *(const float4*)c1p;
            float4 c1b = *(const float4*)(c1p + 4);
            float4 c0a = *(const float4*)c0p;
            float4 c0b = *(const float4*)(c0p + 4);
            float cc1[8] = {c1a.x, c1a.y, c1a.z, c1a.w, c1b.x, c1b.y, c1b.z, c1b.w};
            float cc0[8] = {c0a.x, c0a.y, c0a.z, c0a.w, c0b.x, c0b.y, c0b.z, c0b.w};
            short8 av;
#pragma unroll
            for (int j = 0; j < 8; ++j)
                av[j] = (short)f2bf(swishf(cc1[j] * v[j] + cc0[j]));
            a_all[ks][i] = av;
        }
    }

    const int c0a = wch + (l16 << 3);
#pragma unroll
    for (int jh = 0; jh < 2; ++jh) {
        floatx4 acc1[2][4];
#pragma unroll
        for (int i = 0; i < 2; ++i)
#pragma unroll
            for (int j = 0; j < 4; ++j) acc1[i][j] = zed;
#pragma unroll
        for (int ks = 0; ks < 4; ++ks) {
            int k = (ks << 5) + (quad << 3);
            short8 b[4];
#pragma unroll
            for (int j = 0; j < 4; ++j) {
                int pc = c0a + (jh << 2) + j;
                b[j] = *(const short8*)(W1 + (size_t)pc * HH + k);
            }
#pragma unroll
            for (int i = 0; i < 2; ++i)
#pragma unroll
                for (int j = 0; j < 4; ++j)
                    acc1[i][j] = __builtin_amdgcn_mfma_f32_16x16x32_bf16(a_all[ks][i], b[j],
                                                                         acc1[i][j], 0, 0, 0);
        }
        float4 b4 = *(const float4*)(b1 + c0a + (jh << 2));
        float bv[4] = {b4.x, b4.y, b4.z, b4.w};
#pragma unroll
        for (int i = 0; i < 2; ++i) {
#pragma unroll
            for (int reg = 0; reg < 4; ++reg) {
                int lr = wrh + (i << 4) + (quad << 2) + reg;
                float o[4];
#pragma unroll
                for (int j = 0; j < 4; ++j) o[j] = swishf(acc1[i][j][reg] + bv[j]);
                *(uint2*)(&smem[lr * (MM + 8) + c0a + (jh << 2)]) = pack4(o);
            }
        }
    }
    __syncthreads();

    // ---- phase B: h' = swish(t @ W2^T + b2) + res ----
    floatx4 acc2[2][4];
#pragma unroll
    for (int i = 0; i < 2; ++i)
#pragma unroll
        for (int j = 0; j < 4; ++j) acc2[i][j] = zed;
#pragma unroll
    for (int ks = 0; ks < MM / 32; ++ks) {
        int k = (ks << 5) + (quad << 3);
        short8 a[2], b[4];
#pragma unroll
        for (int i = 0; i < 2; ++i)
            a[i] = *(const short8*)(&smem[(wrh + (i << 4) + l16) * (MM + 8) + k]);
#pragma unroll
        for (int j = 0; j < 4; ++j) {
            int pc = wc2 + (l16 << 2) + j;
            b[j] = *(const short8*)(W2 + (size_t)pc * MM + k);
        }
#pragma unroll
        for (int i = 0; i < 2; ++i)
#pragma unroll
            for (int j = 0; j < 4; ++j)
                acc2[i][j] =
                    __builtin_amdgcn_mfma_f32_16x16x32_bf16(a[i], b[j], acc2[i][j], 0, 0, 0);
    }
    __syncthreads();  // all t-reads done; smem can be reused as h'

    const int co = wc2 + (l16 << 2);
    {
        float4 b4 = *(const float4*)(b2 + co);
        float bv[4] = {b4.x, b4.y, b4.z, b4.w};
#pragma unroll
        for (int i = 0; i < 2; ++i) {
            int rb = rowBase + wrh + (i << 4) + (quad << 2);
#pragma unroll
            for (int reg = 0; reg < 4; ++reg) {
                int r = rb + reg;
                if (r < NN) {
                    uint2 rv = *(const uint2*)(hb + (size_t)r * HH + co);
                    float2 r01 = bf2f2(rv.x), r23 = bf2f2(rv.y);
                    float o[4];
                    o[0] = swishf(acc2[i][0][reg] + bv[0]) + r01.x;
                    o[1] = swishf(acc2[i][1][reg] + bv[1]) + r01.y;
                    o[2] = swishf(acc2[i][2][reg] + bv[2]) + r23.x;
                    o[3] = swishf(acc2[i][3][reg] + bv[3]) + r23.y;
                    uint2 pk = pack4(o);
                    *(uint2*)(hb + (size_t)r * HH + co) = pk;
                    if (writeF)
                        *(float4*)(h_out + (size_t)r * HH + co) =
                            make_float4(o[0], o[1], o[2], o[3]);
                    int lr = wrh + (i << 4) + (quad << 2) + reg;
                    *(uint2*)(&smem[lr * 136 + co]) = pk;
                }
            }
        }
    }

    // ---- phase C: y_next = bf16((h' @ Wc^T) * dinv) ----
    if (doConv) {
        __syncthreads();
        floatx4 acc3[2][4];
#pragma unroll
        for (int i = 0; i < 2; ++i)
#pragma unroll
            for (int j = 0; j < 4; ++j) acc3[i][j] = zed;
#pragma unroll
        for (int ks = 0; ks < 4; ++ks) {
            int k = (ks << 5) + (quad << 3);
            short8 a[2], b[4];
#pragma unroll
            for (int i = 0; i < 2; ++i)
                a[i] = *(const short8*)(&smem[(wrh + (i << 4) + l16) * 136 + k]);
#pragma unroll
            for (int j = 0; j < 4; ++j) {
                int pc = wc2 + (l16 << 2) + j;
                b[j] = *(const short8*)(Wc + (size_t)pc * HH + k);
            }
#pragma unroll
            for (int i = 0; i < 2; ++i)
#pragma unroll
                for (int j = 0; j < 4; ++j)
                    acc3[i][j] =
                        __builtin_amdgcn_mfma_f32_16x16x32_bf16(a[i], b[j], acc3[i][j], 0, 0, 0);
        }
#pragma unroll
        for (int i = 0; i < 2; ++i) {
            int rb = rowBase + wrh + (i << 4) + (quad << 2);
#pragma unroll
            for (int reg = 0; reg < 4; ++reg) {
                int r = rb + reg;
                if (r < NN) {
                    float dv = dinv[r];
                    float o[4];
#pragma unroll
                    for (int j = 0; j < 4; ++j) o[j] = acc3[i][j][reg] * dv;
                    *(uint2*)(y_out + (size_t)r * HH + co) = pack4(o);
                }
            }
        }
    }
}

extern "C" void kernel_launch(void* const* d_in, const int* in_sizes, int n_in,
                              void* d_out, int out_size, void* d_ws, size_t ws_size,
                              hipStream_t stream) {
    const float* x = (const float*)d_in[0];
    const int* ei = (const int*)d_in[1];
    const int* batch = (const int*)d_in[2];
    const float* z_embed = (const float*)d_in[3];
    const float* extra_w = (const float*)d_in[4];
    const float* extra_b = (const float*)d_in[5];
    const float* conv_w = (const float*)d_in[6];
    const float* conv_b = (const float*)d_in[7];
    const float* gamma = (const float*)d_in[8];
    const float* beta = (const float*)d_in[9];
    const float* mean_scale = (const float*)d_in[10];
    const float* mlp_w1 = (const float*)d_in[11];
    const float* mlp_b1 = (const float*)d_in[12];
    const float* mlp_w2 = (const float*)d_in[13];
    const float* mlp_b2 = (const float*)d_in[14];
    float* h_out = (float*)d_out;

    char* wsB = (char*)d_ws;
    size_t off = 0;
    auto alloc = [&](size_t bytes) -> void* {
        void* p = (void*)(wsB + off);
        off = (off + bytes + 255) & ~(size_t)255;
        return p;
    };
    float* dinv = (float*)alloc((size_t)NN * 4);
    int* deg = (int*)alloc((size_t)NN * 4);
    int* cursor = (int*)alloc((size_t)NN * 4);
    int* rowptr = (int*)alloc((size_t)(NN + 1) * 4);
    int* bsum = (int*)alloc(128 * 4);
    int* boff = (int*)alloc(128 * 4);
    int* col = (int*)alloc((size_t)EE * 4);
    int* gptr = (int*)alloc((size_t)(GG + 1) * 4);
    float* c1t = (float*)alloc((size_t)GG * HH * 4);
    float* c0t = (float*)alloc((size_t)GG * HH * 4);
    unsigned short* wb =
        (unsigned short*)alloc((size_t)(LL * (HH * HH + MM * HH + HH * MM)) * 2);
    unsigned short* cwb = wb;
    unsigned short* w1b = wb + (size_t)LL * HH * HH;
    unsigned short* w2b = w1b + (size_t)LL * MM * HH;
    unsigned short* hb = (unsigned short*)alloc((size_t)NN * HH * 2);    // bf16 residual
    unsigned short* ybuf = (unsigned short*)alloc((size_t)NN * HH * 2);  // y (conv out)
    unsigned short* aggb = (unsigned short*)alloc((size_t)NN * HH * 2);  // agg bf16

    hipMemsetAsync(deg, 0, (size_t)NN * 4, stream);
    hipMemsetAsync(cursor, 0, (size_t)NN * 4, stream);

    k_embed<<<(NN * 32 + 255) / 256, 256, 0, stream>>>(x, z_embed, extra_w, extra_b, hb);
    {
        int n1 = LL * HH * HH, n2 = LL * MM * HH, n3 = LL * HH * MM;
        int nt = n1 + n2 + n3;
        k_f2bf3<<<(nt + 255) / 256, 256, 0, stream>>>(conv_w, cwb, n1, mlp_w1, w1b, n2,
                                                      mlp_w2, w2b, n3);
    }
    k_degree_p<<<1024, 256, 0, stream>>>(ei + EE, deg);
    k_dinv<<<(NN + 255) / 256, 256, 0, stream>>>(deg, dinv);
    k_scan1<<<SCAN_NB, 256, 0, stream>>>(deg, bsum);
    k_scan2<<<1, 128, 0, stream>>>(bsum, boff);
    k_scan3<<<SCAN_NB, 256, 0, stream>>>(deg, boff, rowptr);
    k_fill_p<<<1024, 256, 0, stream>>>(ei, rowptr, cursor, col);
    k_gptr<<<(NN + 255) / 256, 256, 0, stream>>>(batch, gptr);

    int gconv = (NN + 127) / 128;
    int gmega = (NN + 63) / 64;
    k_conv<<<gconv, 256, 0, stream>>>(hb, cwb, dinv, ybuf);
    for (int i = 0; i < LL; ++i) {
        k_agg<<<(NN + 3) / 4, 256, 0, stream>>>(ybuf, rowptr, col, dinv,
                                                conv_b + (size_t)i * HH, aggb);
        k_stats<<<GG, 512, 0, stream>>>(aggb, gptr, mean_scale + (size_t)i * HH,
                                        gamma + (size_t)i * HH, beta + (size_t)i * HH, c1t,
                                        c0t);
        k_mega<<<gmega, 256, 0, stream>>>(
            aggb, batch, c1t, c0t, w1b + (size_t)i * MM * HH, mlp_b1 + (size_t)i * MM,
            w2b + (size_t)i * HH * MM, mlp_b2 + (size_t)i * HH,
            cwb + (size_t)(i + 1 < LL ? i + 1 : 0) * HH * HH, dinv, hb, h_out, ybuf,
            i == LL - 1 ? 1 : 0, i < LL - 1 ? 1 : 0);
    }
}